// Round 2
// baseline (255.569 us; speedup 1.0000x reference)
//
#include <hip/hip_runtime.h>

#define BB 2
#define NN 32768
#define EN 32768

typedef unsigned int u32;
typedef __attribute__((ext_vector_type(8)))  short bf16x8;
typedef __attribute__((ext_vector_type(2)))  float f32x2;
typedef __attribute__((ext_vector_type(4)))  float f32x4;

union U4 { uint4 u; bf16x8 h; };

// Single-instruction bf16 pack (no gfx950 builtin; RNE, same numerics).
__device__ __forceinline__ u32 pk2(float lo, float hi) {
    u32 r;
    asm("v_cvt_pk_bf16_f32 %0, %1, %2" : "=v"(r) : "v"(lo), "v"(hi));
    return r;
}

// Sum over the 4 lanes {l, l^16, l^32, l^48}: ds_swizzle xor16 (within each
// 32-lane group) + permlane32_swap (VALU) for the cross-half exchange.
__device__ __forceinline__ float red4(float v) {
    int x = __builtin_amdgcn_ds_swizzle(__builtin_bit_cast(int, v), 0x401F);
    v += __builtin_bit_cast(float, x);
    float w = v;
    asm("v_permlane32_swap_b32 %0, %1" : "+v"(v), "+v"(w));
    return v + w;
}

__device__ __forceinline__ f32x4 MF16(bf16x8 a, bf16x8 b, f32x4 c) {
    return __builtin_amdgcn_mfma_f32_16x16x32_bf16(a, b, c, 0, 0, 0);
}

// ---------------------------------------------------------------------------
// 16x16x32 MFMA engine. Lane (e = lane&15, g = lane>>4).
// C/D: col = e, row(r,g) = 4g + r [m89-verified]. Two independent MFMAs per
// hidden layer (out-features 0..15 / 16..31), full K=32 each.
// k-slot -> feature permutation: f(t,g,j) = 32t + 16*(j>>2) + 4g + (j&3).
// Under this pi, C regs map to the next layer's B-frag by IDENTITY:
//   B j=0..3  <- D_lo r=0..3  (features 4g+r)
//   B j=4..7  <- D_hi r=0..3  (features 16+4g+r)
// (Relies on A and B sharing the hardware k-slot mapping — the same symmetry
// the verified 32x32 pi layout used.)
// Weights are the A operand (lane&15 = out-feature); biases enter via MFMA C
// in NATURAL order (float4 at +4g / +16+4g), read directly from global (L1
// broadcast, prefetched one layer ahead).
// ---------------------------------------------------------------------------
template<bool LN>
__device__ __forceinline__ bf16x8 transform16(f32x4 lo, f32x4 hi)
{
    f32x2 q0 = {lo[0],lo[1]}, q1 = {lo[2],lo[3]};
    f32x2 q2 = {hi[0],hi[1]}, q3 = {hi[2],hi[3]};
    const f32x2 zz = {0.f, 0.f};
    q0 = __builtin_elementwise_max(q0, zz); q1 = __builtin_elementwise_max(q1, zz);
    q2 = __builtin_elementwise_max(q2, zz); q3 = __builtin_elementwise_max(q3, zz);
    if (LN) {
        f32x2 sv = (q0+q1)+(q2+q3);
        f32x2 tv = __builtin_elementwise_fma(q0,q0,
                   __builtin_elementwise_fma(q1,q1,
                   __builtin_elementwise_fma(q2,q2, q3*q3)));
        float s = red4(sv.x + sv.y);
        float t = red4(tv.x + tv.y);
        float mu  = s * (1.f/32.f);
        float var = fmaf(-mu, mu, t * (1.f/32.f));
        float rs  = rsqrtf(var + 1e-5f);
        float nt  = -mu * rs;
        f32x2 rs2 = {rs, rs}, nt2 = {nt, nt};
        q0 = __builtin_elementwise_fma(q0, rs2, nt2);
        q1 = __builtin_elementwise_fma(q1, rs2, nt2);
        q2 = __builtin_elementwise_fma(q2, rs2, nt2);
        q3 = __builtin_elementwise_fma(q3, rs2, nt2);
    }
    U4 c;
    c.u.x = pk2(q0.x,q0.y); c.u.y = pk2(q1.x,q1.y);
    c.u.z = pk2(q2.x,q2.y); c.u.w = pk2(q3.x,q3.y);
    return c.h;
}

// WL (dwords): [input NT*512][hidden 32*512][out 256]
// chunk t half H at (2t+H)*256; hidden layer l half H at HB + l*512 + H*256.
template<int NT, bool LN, bool OUT3>
__device__ __forceinline__ f32x4 mlp16(const bf16x8* bIn, const u32* WL,
    const float* __restrict__ bin, const float* __restrict__ bh,
    const float* __restrict__ bo, int lane, int g)
{
    constexpr int HB = NT*512;
    constexpr int BO = HB + 16384;
    U4 c;
    f32x4 Dlo = *(const f32x4*)(bin + 4*g);
    f32x4 Dhi = *(const f32x4*)(bin + 16 + 4*g);
    #pragma unroll
    for (int t = 0; t < NT; ++t) {
        c.u = *(const uint4*)(WL + (2*t)*256 + lane*4);
        Dlo = MF16(c.h, bIn[t], Dlo);
        c.u = *(const uint4*)(WL + (2*t+1)*256 + lane*4);
        Dhi = MF16(c.h, bIn[t], Dhi);
    }
    c.u = *(const uint4*)(WL + HB + lane*4);        bf16x8 wl0 = c.h;
    c.u = *(const uint4*)(WL + HB + 256 + lane*4);  bf16x8 wh0 = c.h;
    c.u = *(const uint4*)(WL + HB + 512 + lane*4);  bf16x8 wl1 = c.h;
    c.u = *(const uint4*)(WL + HB + 768 + lane*4);  bf16x8 wh1 = c.h;
    f32x4 cbl = *(const f32x4*)(bh + 4*g);
    f32x4 cbh = *(const f32x4*)(bh + 16 + 4*g);
    bf16x8 Bf = transform16<LN>(Dlo, Dhi);
    #pragma unroll 4
    for (int l = 0; l < 32; ++l) {
        const int lp = (l+2 < 32) ? l+2 : 31;
        c.u = *(const uint4*)(WL + HB + lp*512 + lane*4);       bf16x8 nwl = c.h;
        c.u = *(const uint4*)(WL + HB + lp*512 + 256 + lane*4); bf16x8 nwh = c.h;
        const int lb_ = (l+1 < 32) ? l+1 : 31;
        f32x4 nbl = *(const f32x4*)(bh + lb_*32 + 4*g);
        f32x4 nbh = *(const f32x4*)(bh + lb_*32 + 16 + 4*g);
        f32x4 Elo = MF16(wl0, Bf, cbl);
        f32x4 Ehi = MF16(wh0, Bf, cbh);
        Bf = transform16<LN>(Elo, Ehi);
        wl0 = wl1; wh0 = wh1; wl1 = nwl; wh1 = nwh; cbl = nbl; cbh = nbh;
    }
    c.u = *(const uint4*)(WL + BO + lane*4);
    f32x4 Co;
    if (OUT3) {
        Co = (f32x4){0.f, 0.f, 0.f, 0.f};
        if (g == 0) { Co[0] = bo[0]; Co[1] = bo[1]; Co[2] = bo[2]; }
    } else {
        Co = *(const f32x4*)(bo + 4*g);
    }
    return MF16(c.h, Bf, Co);
}

// ---------------------------------------------------------------------------
// Weight staging: pure linear DMA, no bias permute pass (biases read from
// global in natural order by the engine).
// ---------------------------------------------------------------------------
__device__ __forceinline__ void stage_w(u32* WL, const u32* __restrict__ Wp,
                                        int wtot, int tid)
{
    const int lane = tid & 63;
    for (int C = (tid >> 6)*256; C < wtot; C += 8*256)
        __builtin_amdgcn_global_load_lds(
            (const __attribute__((address_space(1))) u32*)(Wp + C + lane*4),
            (__attribute__((address_space(3))) u32*)(WL + C), 16, 0, 0);
    __syncthreads();
}

// ---------------------------------------------------------------------------
// Weight packing to the 16x16 pi layout + LN-gamma fold.
// dst dword t: input region [0, NT*512): chunk tt=t>>9, half H=(t&511)>>8,
// lane=(t&255)>>2 (g=lane>>4, m=H*16+(lane&15)), d=t&3;
// dword = pk2(W[f0][m], W[f0+1][m]), f0 = 32tt + 16*(d>>1) + 4g + 2*(d&1).
// Hidden: same with l = (t-binW)>>9, f0 without the 32tt term.
// Out: M-lo only (256 dwords).
// ---------------------------------------------------------------------------
__device__ __forceinline__ void pack_body16(
    const float* __restrict__ Win, const float* __restrict__ Wh,
    const float* __restrict__ Wout, const float* __restrict__ lng,
    u32* __restrict__ dst, int din, int dout, int NT, int lb, int tid)
{
    int t = lb * 256 + tid;
    int binW = NT * 512;
    int tot = binW + 16384 + 256;
    if (t >= tot) return;
    float lo, hi;
    if (t < binW) {
        int tt = t>>9, v = t&511, H = v>>8, rem = v&255, ln_ = rem>>2, d = rem&3;
        int g = ln_>>4, m = (ln_&15) + H*16;
        int f0 = 32*tt + 16*(d>>1) + 4*g + 2*(d&1);
        lo = (f0   < din) ? Win[f0*32 + m]     : 0.f;
        hi = (f0+1 < din) ? Win[(f0+1)*32 + m] : 0.f;
    } else if (t < binW + 16384) {
        int u = t - binW, l = u>>9, v = u&511, H = v>>8, rem = v&255;
        int ln_ = rem>>2, d = rem&3;
        int g = ln_>>4, m = (ln_&15) + H*16;
        int f0 = 16*(d>>1) + 4*g + 2*(d&1);
        lo = Wh[l*1024 + f0*32 + m];
        hi = Wh[l*1024 + (f0+1)*32 + m];
        if (lng) { lo *= lng[l*32 + f0]; hi *= lng[l*32 + f0 + 1]; }
    } else {
        int u = t - binW - 16384, ln_ = u>>2, d = u&3;
        int g = ln_>>4, m = ln_&15;
        int f0 = 16*(d>>1) + 4*g + 2*(d&1);
        lo = (m < dout) ? Wout[f0*dout + m]     : 0.f;
        hi = (m < dout) ? Wout[(f0+1)*dout + m] : 0.f;
        if (lng) { lo *= lng[1024 + f0]; hi *= lng[1024 + f0 + 1]; }
    }
    dst[t] = pk2(lo, hi);
}

__device__ __forceinline__ void fold_body(
    const float* __restrict__ Wh,   const float* __restrict__ bh,
    const float* __restrict__ Wout, const float* __restrict__ bout,
    const float* __restrict__ lnb,  float* __restrict__ fb, int lb, int tid)
{
    int j = lb * 256 + tid;
    if (j < 1024) {
        int l = j >> 5, jj = j & 31;
        float acc = bh[j];
        #pragma unroll
        for (int k = 0; k < 32; ++k)
            acc = fmaf(lnb[l*32 + k], Wh[l*1024 + k*32 + jj], acc);
        fb[j] = acc;
    } else if (j < 1024 + 16) {
        int jj = j - 1024;
        float acc = bout[jj];
        #pragma unroll
        for (int k = 0; k < 32; ++k)
            acc = fmaf(lnb[1024 + k], Wout[k*16 + jj], acc);
        fb[j] = acc;
    }
}

// block ranges: ne 67 | ed 67 | pe 69 | pv 69 | de 67 | foldpe 5 | foldpv 5
__global__ __launch_bounds__(256) void prep_kernel(
    const float* ne_Win, const float* ne_Wh, const float* ne_Wout,
    const float* ed_Win, const float* ed_Wh, const float* ed_Wout,
    const float* pe_Win, const float* pe_Wh, const float* pe_Wout,
    const float* pe_lng, const float* pe_lnb, const float* pe_bh, const float* pe_bout,
    const float* pv_Win, const float* pv_Wh, const float* pv_Wout,
    const float* pv_lng, const float* pv_lnb, const float* pv_bh, const float* pv_bout,
    const float* de_Win, const float* de_Wh, const float* de_Wout,
    u32* Wne, u32* Wed, u32* Wpe, u32* Wpv, u32* Wde,
    float* Fpe, float* Fpv)
{
    int bx = blockIdx.x, tid = threadIdx.x;
    if      (bx < 67)  pack_body16(ne_Win, ne_Wh, ne_Wout, nullptr, Wne,  7, 16, 1, bx,       tid);
    else if (bx < 134) pack_body16(ed_Win, ed_Wh, ed_Wout, nullptr, Wed,  5, 16, 1, bx - 67,  tid);
    else if (bx < 203) pack_body16(pe_Win, pe_Wh, pe_Wout, pe_lng,  Wpe, 49, 16, 2, bx - 134, tid);
    else if (bx < 272) pack_body16(pv_Win, pv_Wh, pv_Wout, pv_lng,  Wpv, 33, 16, 2, bx - 203, tid);
    else if (bx < 339) pack_body16(de_Win, de_Wh, de_Wout, nullptr, Wde, 16,  3, 1, bx - 272, tid);
    else if (bx < 344) fold_body(pe_Wh, pe_bh, pe_Wout, pe_bout, pe_lnb, Fpe, bx - 339, tid);
    else               fold_body(pv_Wh, pv_bh, pv_Wout, pv_bout, pv_lnb, Fpv, bx - 344, tid);
}

// Pack one 16-feature f32 array into half a K=32 B-frag: lane-group g takes
// features 4g..4g+3 (float4), delivered as two pk2 dwords.
#define WAVE_SETUP \
    const int lane = threadIdx.x & 63; \
    const int wid  = threadIdx.x >> 6; \
    const int el = lane & 15, g = lane >> 4;

// ---------------------------------------------------------------------------
// encode: 512-thr blocks (8 waves x 16 elems), 1024 blocks (node | edge).
// ---------------------------------------------------------------------------
__global__ __launch_bounds__(512, 4) void encode_kernel(
    const float* __restrict__ nodes, const float* __restrict__ edges,
    const float* __restrict__ gvec,
    const int* __restrict__ senders, const int* __restrict__ receivers,
    const u32* __restrict__ Wne, const float* __restrict__ ne_bin,
    const float* __restrict__ ne_bh, const float* __restrict__ ne_bout,
    const u32* __restrict__ Wed, const float* __restrict__ ed_bin,
    const float* __restrict__ ed_bh, const float* __restrict__ ed_bout,
    float* __restrict__ ve, float* __restrict__ ee)
{
    __shared__ __align__(16) u32 SL[17152];
    WAVE_SETUP
    const bool es = blockIdx.x >= 512;
    stage_w(SL, es ? Wed : Wne, 17152, threadIdx.x);
    const int lb = es ? (blockIdx.x - 512) : blockIdx.x;
    const int e = (lb*8 + wid)*16 + el;
    const int b = e >> 15;
    bf16x8 a0;
    {
        uint4 w; w.x = 0u; w.y = 0u; w.z = 0u; w.w = 0u;
        if (!es) {
            // x = [nodes(6), g] -> features 0..6
            if (g == 0) {
                float2 v01 = *(const float2*)(nodes + (size_t)e*6);
                float2 v23 = *(const float2*)(nodes + (size_t)e*6 + 2);
                w.x = pk2(v01.x, v01.y); w.y = pk2(v23.x, v23.y);
            } else if (g == 1) {
                float2 v45 = *(const float2*)(nodes + (size_t)e*6 + 4);
                w.x = pk2(v45.x, v45.y); w.y = pk2(gvec[b], 0.f);
            }
        } else {
            // x = [edge, rel0..2, nrm] -> features 0..4
            if (g < 2) {
                int s = senders[e], r = receivers[e];
                const float* ps = nodes + ((size_t)b*NN + s)*6;
                const float* pr = nodes + ((size_t)b*NN + r)*6;
                float2 s01 = *(const float2*)ps; float s2v = ps[2];
                float2 r01 = *(const float2*)pr; float r2v = pr[2];
                float r0 = s01.x - r01.x, r1 = s01.y - r01.y, r2 = s2v - r2v;
                if (g == 0) {
                    w.x = pk2(edges[e], r0); w.y = pk2(r1, r2);
                } else {
                    w.x = pk2(sqrtf(r0*r0 + r1*r1 + r2*r2), 0.f);
                }
            }
        }
        U4 c; c.u = w; a0 = c.h;
    }
    f32x4 O = mlp16<1, false, false>(&a0, SL,
                es ? ed_bin : ne_bin, es ? ed_bh : ne_bh,
                es ? ed_bout : ne_bout, lane, g);
    float4 s1;
    s1.x = fmaxf(O[0], 0.f); s1.y = fmaxf(O[1], 0.f);
    s1.z = fmaxf(O[2], 0.f); s1.w = fmaxf(O[3], 0.f);
    *(float4*)((es ? ee : ve) + (size_t)e*16 + 4*g) = s1;
}

// ---------------------------------------------------------------------------
// edge_update: 512-thr blocks (8 waves x 16 elems), 512 blocks.
// ---------------------------------------------------------------------------
__global__ __launch_bounds__(512, 4) void edge_update_kernel(
    const float* __restrict__ gvec,
    const int* __restrict__ senders, const int* __restrict__ receivers,
    const float* __restrict__ ve, float* __restrict__ ee, float* __restrict__ agg,
    const u32* __restrict__ Wp, const float* __restrict__ bin,
    const float* __restrict__ fb)
{
    __shared__ __align__(16) u32 SL[17664 + 8*272];
    u32* WL = SL;
    WAVE_SETUP
    float* X = (float*)(SL + 17664) + wid*272;
    stage_w(WL, Wp, 17664, threadIdx.x);
    const int e0 = (blockIdx.x*8 + wid)*16;
    const int e  = e0 + el;
    const int b  = e >> 15;
    const int s  = senders[e], r_ = receivers[e];
    float4 fee = *(const float4*)(ee + (size_t)e*16 + 4*g);
    float4 fvs = *(const float4*)(ve + ((size_t)b*NN + s )*16 + 4*g);
    float4 fvr = *(const float4*)(ve + ((size_t)b*NN + r_)*16 + 4*g);
    bf16x8 a[2];
    {
        uint4 w;
        w.x = pk2(fee.x, fee.y); w.y = pk2(fee.z, fee.w);
        w.z = pk2(fvs.x, fvs.y); w.w = pk2(fvs.z, fvs.w);
        U4 c; c.u = w; a[0] = c.h;
        w.x = pk2(fvr.x, fvr.y); w.y = pk2(fvr.z, fvr.w);
        w.z = (g == 0) ? pk2(gvec[b], 0.f) : 0u; w.w = 0u;
        c.u = w; a[1] = c.h;
    }
    f32x4 O = mlp16<2, true, false>(a, WL, bin, fb, fb + 1024, lane, g);
    float4 s1;
    s1.x = fmaxf(O[0], 0.f); s1.y = fmaxf(O[1], 0.f);
    s1.z = fmaxf(O[2], 0.f); s1.w = fmaxf(O[3], 0.f);
    *(float4*)(ee + (size_t)e*16 + 4*g) = s1;
    // Transpose through wave-private LDS so each atomic instruction hits 4
    // receiver lines (16 lanes share a receiver, features contiguous).
    *(float4*)(X + el*17 + 4*g) = s1;
    const int feat = lane & 15;
    #pragma unroll
    for (int rr = 0; rr < 4; ++rr) {
        int m = (lane >> 4) + rr*4;            // element index within group
        float v = X[m*17 + feat];
        int rc = __shfl(r_, m);                // lane m (m<16) holds receivers
        atomicAdd(agg + ((size_t)b*NN + rc)*16 + feat, v);
    }
}

// ---------------------------------------------------------------------------
// node_update: 512-thr blocks (8 waves x 16 elems), 512 blocks.
// DEC=true: after pv MLP, barrier + restage decode weights over the SAME WL
// region (keeps LDS <= 80KB -> 2 blocks/CU), then fused decode. Node-output
// regs ARE decode's B-frag j0..3 under pi16 (identity).
// ---------------------------------------------------------------------------
template<bool DEC>
__global__ __launch_bounds__(512, 4) void node_update_kernel(
    const float* __restrict__ gvec,
    const float* __restrict__ agg, float* __restrict__ ve,
    const u32* __restrict__ Wp, const float* __restrict__ bin,
    const float* __restrict__ fb,
    const u32* __restrict__ Wde, const float* __restrict__ de_bin,
    const float* __restrict__ de_bh, const float* __restrict__ de_bout,
    float* __restrict__ out)
{
    __shared__ __align__(16) u32 SL[17664];
    WAVE_SETUP
    stage_w(SL, Wp, 17664, threadIdx.x);
    const int e = (blockIdx.x*8 + wid)*16 + el;
    const int b = e >> 15;
    float4 fa = *(const float4*)(agg + (size_t)e*16 + 4*g);
    float4 fv = *(const float4*)(ve  + (size_t)e*16 + 4*g);
    bf16x8 a[2];
    {
        uint4 w;
        w.x = pk2(fa.x, fa.y); w.y = pk2(fa.z, fa.w);
        w.z = pk2(fv.x, fv.y); w.w = pk2(fv.z, fv.w);
        U4 c; c.u = w; a[0] = c.h;
        w.x = (g == 0) ? pk2(gvec[b], 0.f) : 0u;
        w.y = 0u; w.z = 0u; w.w = 0u;
        c.u = w; a[1] = c.h;
    }
    f32x4 O = mlp16<2, true, false>(a, SL, bin, fb, fb + 1024, lane, g);
    if (!DEC) {
        float4 s1;
        s1.x = fmaxf(O[0], 0.f); s1.y = fmaxf(O[1], 0.f);
        s1.z = fmaxf(O[2], 0.f); s1.w = fmaxf(O[3], 0.f);
        *(float4*)(ve + (size_t)e*16 + 4*g) = s1;
    } else {
        __syncthreads();                       // all waves done with pv weights
        stage_w(SL, Wde, 17152, threadIdx.x);  // restage decode (ends in barrier)
        bf16x8 d0;
        {
            float o0 = fmaxf(O[0], 0.f), o1 = fmaxf(O[1], 0.f);
            float o2 = fmaxf(O[2], 0.f), o3 = fmaxf(O[3], 0.f);
            U4 c;
            c.u.x = pk2(o0, o1); c.u.y = pk2(o2, o3);
            c.u.z = 0u; c.u.w = 0u;
            d0 = c.h;
        }
        f32x4 O2 = mlp16<1, false, true>(&d0, SL, de_bin, de_bh, de_bout, lane, g);
        if (g == 0) {
            out[(size_t)e*3 + 0] = fmaxf(O2[0], 0.f);
            out[(size_t)e*3 + 1] = fmaxf(O2[1], 0.f);
            out[(size_t)e*3 + 2] = fmaxf(O2[2], 0.f);
        }
    }
}

// ---------------------------------------------------------------------------
// launch
// ---------------------------------------------------------------------------
extern "C" void kernel_launch(void* const* d_in, const int* in_sizes, int n_in,
                              void* d_out, int out_size, void* d_ws, size_t ws_size,
                              hipStream_t stream)
{
    const float* nodes     = (const float*)d_in[0];
    const float* edges     = (const float*)d_in[1];
    const float* gvec      = (const float*)d_in[2];
    const int*   senders   = (const int*)  d_in[3];
    const int*   receivers = (const int*)  d_in[4];

    const float* ne_Win  = (const float*)d_in[5];
    const float* ne_bin  = (const float*)d_in[6];
    const float* ne_Wh   = (const float*)d_in[7];
    const float* ne_bh   = (const float*)d_in[8];
    const float* ne_Wout = (const float*)d_in[9];
    const float* ne_bout = (const float*)d_in[10];

    const float* ed_Win  = (const float*)d_in[11];
    const float* ed_bin  = (const float*)d_in[12];
    const float* ed_Wh   = (const float*)d_in[13];
    const float* ed_bh   = (const float*)d_in[14];
    const float* ed_Wout = (const float*)d_in[15];
    const float* ed_bout = (const float*)d_in[16];

    const float* pe_Win  = (const float*)d_in[17];
    const float* pe_bin  = (const float*)d_in[18];
    const float* pe_Wh   = (const float*)d_in[19];
    const float* pe_bh   = (const float*)d_in[20];
    const float* pe_Wout = (const float*)d_in[21];
    const float* pe_bout = (const float*)d_in[22];
    const float* pe_lng  = (const float*)d_in[23];
    const float* pe_lnb  = (const float*)d_in[24];

    const float* pv_Win  = (const float*)d_in[25];
    const float* pv_bin  = (const float*)d_in[26];
    const float* pv_Wh   = (const float*)d_in[27];
    const float* pv_bh   = (const float*)d_in[28];
    const float* pv_Wout = (const float*)d_in[29];
    const float* pv_bout = (const float*)d_in[30];
    const float* pv_lng  = (const float*)d_in[31];
    const float* pv_lnb  = (const float*)d_in[32];

    const float* de_Win  = (const float*)d_in[33];
    const float* de_bin  = (const float*)d_in[34];
    const float* de_Wh   = (const float*)d_in[35];
    const float* de_bh   = (const float*)d_in[36];
    const float* de_Wout = (const float*)d_in[37];
    const float* de_bout = (const float*)d_in[38];

    // workspace: ve | ee | agg0 | agg1 (4 MB each) | packed weights | biases
    float* ve   = (float*)d_ws;
    float* ee   = ve   + (size_t)1048576;
    float* agg0 = ee   + (size_t)1048576;
    float* agg1 = agg0 + (size_t)1048576;
    u32* Wne = (u32*)(agg1 + (size_t)1048576);
    u32* Wed = Wne + 17152;
    u32* Wpe = Wed + 17152;
    u32* Wpv = Wpe + 17664;
    u32* Wde = Wpv + 17664;
    float* Fpe = (float*)(Wde + 17152);
    float* Fpv = Fpe + 1040;

    prep_kernel<<<349, dim3(256), 0, stream>>>(
        ne_Win, ne_Wh, ne_Wout,
        ed_Win, ed_Wh, ed_Wout,
        pe_Win, pe_Wh, pe_Wout, pe_lng, pe_lnb, pe_bh, pe_bout,
        pv_Win, pv_Wh, pv_Wout, pv_lng, pv_lnb, pv_bh, pv_bout,
        de_Win, de_Wh, de_Wout,
        Wne, Wed, Wpe, Wpv, Wde, Fpe, Fpv);

    // zero both agg ping-pong buffers in one shot
    hipMemsetAsync(agg0, 0, (size_t)2 * 1048576 * sizeof(float), stream);

    encode_kernel<<<1024, dim3(512), 0, stream>>>(nodes, edges, gvec, senders, receivers,
        Wne, ne_bin, ne_bh, ne_bout,
        Wed, ed_bin, ed_bh, ed_bout, ve, ee);

    // step 0
    edge_update_kernel<<<512, dim3(512), 0, stream>>>(gvec, senders, receivers,
        ve, ee, agg0, Wpe, pe_bin, Fpe);
    node_update_kernel<false><<<512, dim3(512), 0, stream>>>(gvec, agg0, ve,
        Wpv, pv_bin, Fpv, Wde, de_bin, de_bh, de_bout, (float*)d_out);
    // step 1 (+ fused decode)
    edge_update_kernel<<<512, dim3(512), 0, stream>>>(gvec, senders, receivers,
        ve, ee, agg1, Wpe, pe_bin, Fpe);
    node_update_kernel<true><<<512, dim3(512), 0, stream>>>(gvec, agg1, ve,
        Wpv, pv_bin, Fpv, Wde, de_bin, de_bh, de_bout, (float*)d_out);
}